// Round 2
// baseline (1128.203 us; speedup 1.0000x reference)
//
#include <hip/hip_runtime.h>
#include <hip/hip_bf16.h>

typedef __hip_bfloat16 bf16;

#define BB   256
#define NN   128
#define IND  9
#define HDD  128
#define NHH  8
#define DHH  16
#define LLY  4
#define OUTD 60
#define FFD  256
#define NPB  8

__device__ __forceinline__ float b2f(bf16 v){ return __bfloat162float(v); }

__device__ __forceinline__ unsigned short f2bf_bits(float f){
    unsigned u = __float_as_uint(f);
    unsigned r = (u + 0x7FFFu + ((u >> 16) & 1u)) >> 16;   // RNE
    return (unsigned short)r;
}

__device__ __forceinline__ float wave_sum(float v){
    #pragma unroll
    for (int m = 32; m; m >>= 1) v += __shfl_xor(v, m, 64);
    return v;
}
__device__ __forceinline__ float wave_max(float v){
    #pragma unroll
    for (int m = 32; m; m >>= 1) v = fmaxf(v, __shfl_xor(v, m, 64));
    return v;
}

// ================= dtype detection =================
// x ~ N(0,1). If buffer holds bf16, low 16-bit half of every 32-bit word is a
// sane bf16 (|v| < 32). If it holds fp32, the low half is mantissa bits ->
// ~47% of them decode to |v| >= 32 (or NaN/Inf). Count over 2048 words.
__global__ __launch_bounds__(64) void k_detect(const unsigned* __restrict__ xw, int* __restrict__ flag)
{
    int lane = threadIdx.x;
    int cnt = 0;
    for (int i = lane; i < 2048; i += 64) {
        unsigned lo = xw[i] & 0xFFFFu;
        float v = __uint_as_float(lo << 16);
        if (!(fabsf(v) < 32.f)) cnt++;     // catches NaN/Inf too
    }
    float c = wave_sum((float)cnt);
    if (lane == 0) *flag = (c < 64.f) ? 1 : 0;   // 1 = bf16, 0 = fp32
}

// ================= input -> fp32 conversion =================
struct SrcPtrs { const void* p[28]; };
__device__ const int CVT_SZ[28] = {
    294912,1152,128,128,128,128,128,65536,512,512,512,512,
    131072,1024,131072,512,128,128,16384,128,8192,64,3840,60,
    16384,16384,16384,16384};
__device__ const int CVT_OFF[28] = {
    0,294912,296064,296192,296320,296448,296576,296704,362240,362752,363264,363776,
    364288,495360,496384,627456,627968,628096,628224,644608,644736,652928,652992,656832,
    656896,673280,689664,706048};

__global__ __launch_bounds__(256) void k_convert(SrcPtrs S, float* __restrict__ dst,
                                                 const int* __restrict__ flag)
{
    int y = blockIdx.y;
    int sz = CVT_SZ[y];
    int idx = blockIdx.x * 256 + threadIdx.x;
    if (idx >= sz) return;
    float v;
    if (*flag) v = b2f(((const bf16*)S.p[y])[idx]);
    else       v = ((const float*)S.p[y])[idx];
    dst[CVT_OFF[y] + idx] = v;
}

// ================= embedding: conv1d(k=1) + eval BN + relu =================
__global__ __launch_bounds__(128) void k_embed(
    const float* __restrict__ xf, const float* __restrict__ cw, const float* __restrict__ cb,
    const float* __restrict__ bg, const float* __restrict__ bbt,
    const float* __restrict__ bm, const float* __restrict__ bv,
    float* __restrict__ h)
{
    int bn = blockIdx.x, d = threadIdx.x;
    __shared__ float xs[IND];
    if (d < IND) xs[d] = xf[bn * IND + d];
    __syncthreads();
    float acc = cb[d];
    #pragma unroll
    for (int k = 0; k < IND; k++) acc = fmaf(xs[k], cw[d * IND + k], acc);
    acc = (acc - bm[d]) * rsqrtf(bv[d] + 1e-5f) * bg[d] + bbt[d];
    h[bn * HDD + d] = fmaxf(acc, 0.f);
}

// ================= weak adjacency =================
__global__ __launch_bounds__(128) void k_aw(
    const float* __restrict__ wp, const float* __restrict__ wm, float* __restrict__ Aw)
{
    int i = blockIdx.x, j = threadIdx.x;
    float v = wm[i * NN + j] / (1.f + __expf(-wp[i * NN + j]));
    __shared__ float red[2];
    float sm = wave_sum(v);
    if ((j & 63) == 0) red[j >> 6] = sm;
    __syncthreads();
    float tot = red[0] + red[1];
    Aw[i * NN + j] = v / (tot + 1e-5f);
}

// ================= hp = h @ W[i]; s,t scores; packed bf16 pairs =================
__global__ __launch_bounds__(128) void k_hp(
    const float* __restrict__ h, const float* __restrict__ W,
    const float* __restrict__ asrc, const float* __restrict__ adst,
    unsigned* __restrict__ hp_pair, float* __restrict__ sv, float* __restrict__ tv)
{
    int base = blockIdx.x * NPB;
    int e = threadIdx.x;
    float acc[NPB];
    #pragma unroll
    for (int n = 0; n < NPB; n++) acc[n] = 0.f;
    for (int k = 0; k < HDD; k += 4) {
        float w0 = W[(k + 0) * HDD + e];
        float w1 = W[(k + 1) * HDD + e];
        float w2 = W[(k + 2) * HDD + e];
        float w3 = W[(k + 3) * HDD + e];
        #pragma unroll
        for (int n = 0; n < NPB; n++) {
            const float4 hv = *(const float4*)&h[(base + n) * HDD + k];  // wave-uniform
            acc[n] = fmaf(hv.x, w0, acc[n]);
            acc[n] = fmaf(hv.y, w1, acc[n]);
            acc[n] = fmaf(hv.z, w2, acc[n]);
            acc[n] = fmaf(hv.w, w3, acc[n]);
        }
    }
    __shared__ float hpr[NPB][HDD];
    #pragma unroll
    for (int n = 0; n < NPB; n++) hpr[n][e] = acc[n];
    __syncthreads();
    #pragma unroll
    for (int idx = e; idx < NPB * 64; idx += 128) {
        int n = idx >> 6, l = idx & 63;
        hp_pair[(base + n) * 64 + l] =
            (unsigned)f2bf_bits(hpr[n][l]) | ((unsigned)f2bf_bits(hpr[n][l + 64]) << 16);
    }
    int n2 = e >> 4, sub = e & 15, hh = sub & 7, which = sub >> 3;
    const float* av = which ? adst : asrc;
    float a = 0.f;
    #pragma unroll
    for (int d2 = 0; d2 < DHH; d2++)
        a = fmaf(hpr[n2][hh * DHH + d2], av[hh * DHH + d2], a);
    int bn = base + n2;
    if (which) tv[bn * NHH + hh] = a; else sv[bn * NHH + hh] = a;
}

// ================= fused attention + LN =================
#define ATTS 130
__global__ __launch_bounds__(256) void k_attn(
    const unsigned* __restrict__ hp_pair, const float* __restrict__ sv, const float* __restrict__ tv,
    const float* __restrict__ Aw, const float* __restrict__ sa, const float* __restrict__ ewa,
    const float* __restrict__ lng, const float* __restrict__ lnb, float* __restrict__ g)
{
    int b = blockIdx.x, half = blockIdx.y;
    int tid = threadIdx.x, lane = tid & 63, wv = tid >> 6;
    __shared__ unsigned hps[NN * 64];
    __shared__ float ts[NHH][NN];
    __shared__ float2 att[4][4 * ATTS];
    for (int idx = tid; idx < NN * 64; idx += 256) hps[idx] = hp_pair[b * NN * 64 + idx];
    for (int idx = tid; idx < NN * NHH; idx += 256) ts[idx & 7][idx >> 3] = tv[b * NN * NHH + idx];
    __syncthreads();
    const int p = lane >> 4;
    float lnG0 = lng[lane], lnG1 = lng[lane + 64];
    float lnB0 = lnb[lane], lnB1 = lnb[lane + 64];
    for (int i = half * 64 + wv; i < half * 64 + 64; i += 4) {
        int bn = b * NN + i;
        float ew0 = ewa[i * NN + lane], ew1 = ewa[i * NN + lane + 64];
        bool m0 = sa[i * NN + lane] > 0.f, m1 = sa[i * NN + lane + 64] > 0.f;
        #pragma unroll
        for (int hh = 0; hh < 4; hh++) {
            float siA = sv[bn * NHH + hh], siB = sv[bn * NHH + hh + 4];
            float eA0 = siA + ts[hh][lane];
            float eA1 = siA + ts[hh][lane + 64];
            float eB0 = siB + ts[hh + 4][lane];
            float eB1 = siB + ts[hh + 4][lane + 64];
            eA0 = (eA0 > 0.f ? eA0 : 0.2f * eA0) + ew0;  eA0 = m0 ? eA0 : -1e30f;
            eA1 = (eA1 > 0.f ? eA1 : 0.2f * eA1) + ew1;  eA1 = m1 ? eA1 : -1e30f;
            eB0 = (eB0 > 0.f ? eB0 : 0.2f * eB0) + ew0;  eB0 = m0 ? eB0 : -1e30f;
            eB1 = (eB1 > 0.f ? eB1 : 0.2f * eB1) + ew1;  eB1 = m1 ? eB1 : -1e30f;
            float mxA = wave_max(fmaxf(eA0, eA1));
            float mxB = wave_max(fmaxf(eB0, eB1));
            float pA0 = m0 ? __expf(eA0 - mxA) : 0.f, pA1 = m1 ? __expf(eA1 - mxA) : 0.f;
            float pB0 = m0 ? __expf(eB0 - mxB) : 0.f, pB1 = m1 ? __expf(eB1 - mxB) : 0.f;
            float iA = 1.f / wave_sum(pA0 + pA1);
            float iB = 1.f / wave_sum(pB0 + pB1);
            att[wv][hh * ATTS + lane]      = make_float2(pA0 * iA, pB0 * iB);
            att[wv][hh * ATTS + lane + 64] = make_float2(pA1 * iA, pB1 * iB);
        }
        float st0 = 0.f, st1 = 0.f, wk0 = 0.f, wk1 = 0.f;
        const float* AwRow = Aw + i * NN;
        for (int j = 0; j < NN; j++) {
            unsigned u = hps[j * 64 + lane];
            float f0 = __uint_as_float(u << 16);
            float f1 = __uint_as_float(u & 0xFFFF0000u);
            float2 a = att[wv][p * ATTS + j];
            st0 = fmaf(a.x, f0, st0);
            st1 = fmaf(a.y, f1, st1);
            float awv = AwRow[j];
            wk0 = fmaf(awv, f0, wk0);
            wk1 = fmaf(awv, f1, wk1);
        }
        float g0 = fmaxf(0.6f * st0 + 0.4f * wk0, 0.f);
        float g1 = fmaxf(0.6f * st1 + 0.4f * wk1, 0.f);
        float mean = wave_sum(g0 + g1) * (1.f / HDD);
        float d0 = g0 - mean, d1 = g1 - mean;
        float var = wave_sum(d0 * d0 + d1 * d1) * (1.f / HDD);
        float rs = rsqrtf(var + 1e-5f);
        g[bn * HDD + lane]      = fmaf(d0 * rs, lnG0, lnB0);
        g[bn * HDD + lane + 64] = fmaf(d1 * rs, lnG1, lnB1);
    }
}

// ================= fused FFN (hid tile in LDS) + residual =================
__global__ __launch_bounds__(256) void k_ffn(
    const float* __restrict__ g, const float* __restrict__ w1, const float* __restrict__ b1,
    const float* __restrict__ w2, const float* __restrict__ b2v, float* __restrict__ h)
{
    int base = blockIdx.x * NPB;
    int t = threadIdx.x;
    __shared__ float hid[NPB][FFD];
    float acc[NPB];
    #pragma unroll
    for (int n = 0; n < NPB; n++) acc[n] = 0.f;
    for (int k = 0; k < HDD; k += 4) {
        float w0 = w1[(k + 0) * FFD + t];
        float wA = w1[(k + 1) * FFD + t];
        float wB = w1[(k + 2) * FFD + t];
        float wC = w1[(k + 3) * FFD + t];
        #pragma unroll
        for (int n = 0; n < NPB; n++) {
            const float4 gv = *(const float4*)&g[(base + n) * HDD + k];  // wave-uniform
            acc[n] = fmaf(gv.x, w0, acc[n]);
            acc[n] = fmaf(gv.y, wA, acc[n]);
            acc[n] = fmaf(gv.z, wB, acc[n]);
            acc[n] = fmaf(gv.w, wC, acc[n]);
        }
    }
    float bb = b1[t];
    #pragma unroll
    for (int n = 0; n < NPB; n++) hid[n][t] = fmaxf(acc[n] + bb, 0.f);
    __syncthreads();
    int d = t & 127, hn = t >> 7;
    float a2[4];
    #pragma unroll
    for (int q = 0; q < 4; q++) a2[q] = 0.f;
    for (int k = 0; k < FFD; k++) {
        float wv = w2[k * HDD + d];
        #pragma unroll
        for (int q = 0; q < 4; q++) a2[q] = fmaf(hid[hn * 4 + q][k], wv, a2[q]);  // LDS broadcast
    }
    float bb2 = b2v[d];
    #pragma unroll
    for (int q = 0; q < 4; q++) h[(base + hn * 4 + q) * HDD + d] += a2[q] + bb2;
}

// ================= final LN =================
__global__ __launch_bounds__(64) void k_norm(
    const float* __restrict__ h, const float* __restrict__ ng, const float* __restrict__ nb,
    float* __restrict__ hn)
{
    int bn = blockIdx.x, lane = threadIdx.x;
    float v0 = h[bn * HDD + lane], v1 = h[bn * HDD + lane + 64];
    float mean = wave_sum(v0 + v1) * (1.f / HDD);
    float d0 = v0 - mean, d1 = v1 - mean;
    float var = wave_sum(d0 * d0 + d1 * d1) * (1.f / HDD);
    float rs = rsqrtf(var + 1e-5f);
    hn[bn * HDD + lane]      = fmaf(d0 * rs, ng[lane], nb[lane]);
    hn[bn * HDD + lane + 64] = fmaf(d1 * rs, ng[lane + 64], nb[lane + 64]);
}

// ================= proj + partial node-sum =================
__global__ __launch_bounds__(128) void k_proj(
    const float* __restrict__ hn, const float* __restrict__ pw, float* __restrict__ pooled)
{
    int base = blockIdx.x * NPB;
    int e = threadIdx.x;
    float acc[NPB];
    #pragma unroll
    for (int n = 0; n < NPB; n++) acc[n] = 0.f;
    for (int k = 0; k < HDD; k += 4) {
        float w0 = pw[(k + 0) * HDD + e];
        float wA = pw[(k + 1) * HDD + e];
        float wB = pw[(k + 2) * HDD + e];
        float wC = pw[(k + 3) * HDD + e];
        #pragma unroll
        for (int n = 0; n < NPB; n++) {
            const float4 hv = *(const float4*)&hn[(base + n) * HDD + k];
            acc[n] = fmaf(hv.x, w0, acc[n]);
            acc[n] = fmaf(hv.y, wA, acc[n]);
            acc[n] = fmaf(hv.z, wB, acc[n]);
            acc[n] = fmaf(hv.w, wC, acc[n]);
        }
    }
    float tot = 0.f;
    #pragma unroll
    for (int n = 0; n < NPB; n++) tot += acc[n];
    int b = base / NN;
    atomicAdd(&pooled[b * HDD + e], tot);
}

// ================= head (dtype-flag-aware output) =================
__global__ __launch_bounds__(64) void k_head(
    const float* __restrict__ pooled, const float* __restrict__ pb,
    const float* __restrict__ w1, const float* __restrict__ b1,
    const float* __restrict__ w2, const float* __restrict__ b2,
    void* __restrict__ outv, const int* __restrict__ flag)
{
    int b = blockIdx.x, t = threadIdx.x;
    __shared__ float pl[HDD], r1[64];
    pl[t]      = pooled[b * HDD + t]      * (1.f / NN) + pb[t];
    pl[t + 64] = pooled[b * HDD + t + 64] * (1.f / NN) + pb[t + 64];
    __syncthreads();
    float acc = b1[t];
    for (int k = 0; k < HDD; k++) acc = fmaf(pl[k], w1[k * 64 + t], acc);
    r1[t] = fmaxf(acc, 0.f);
    __syncthreads();
    if (t < OUTD) {
        float a = b2[t];
        for (int k = 0; k < 64; k++) a = fmaf(r1[k], w2[k * OUTD + t], a);
        if (*flag) ((bf16*)outv)[b * OUTD + t] = __float2bfloat16(a);
        else       ((float*)outv)[b * OUTD + t] = a;
    }
}

extern "C" void kernel_launch(void* const* d_in, const int* in_sizes, int n_in,
                              void* d_out, int out_size, void* d_ws, size_t ws_size,
                              hipStream_t stream)
{
    float* ws = (float*)d_ws;
    // params (fp32, converted) live at ws[0 .. 722432)
    float* pf = ws;
    const float* xf   = pf + 0;
    const float* cw   = pf + 294912;
    const float* cb   = pf + 296064;
    const float* bg   = pf + 296192;
    const float* bbt  = pf + 296320;
    const float* bm   = pf + 296448;
    const float* bv   = pf + 296576;
    const float* Wf   = pf + 296704;
    const float* asrc = pf + 362240;
    const float* adst = pf + 362752;
    const float* lng  = pf + 363264;
    const float* lnb  = pf + 363776;
    const float* fw1  = pf + 364288;
    const float* fb1  = pf + 495360;
    const float* fw2  = pf + 496384;
    const float* fb2  = pf + 627456;
    const float* ng   = pf + 627968;
    const float* nb   = pf + 628096;
    const float* pw   = pf + 628224;
    const float* pb   = pf + 644608;
    const float* hw1  = pf + 644736;
    const float* hb1  = pf + 652928;
    const float* hw2  = pf + 652992;
    const float* hb2  = pf + 656832;
    const float* sa   = pf + 656896;
    const float* wm   = pf + 673280;
    const float* wp   = pf + 689664;
    const float* ewa  = pf + 706048;

    int*   flag   = (int*)(ws + 722432);
    float* h      = ws + 722448;             // 4,194,304
    float* g      = h + 4194304;             // 4,194,304
    float* s_buf  = g + 4194304;             // 262,144
    float* t_buf  = s_buf + 262144;          // 262,144
    float* Aw     = t_buf + 262144;          // 16,384
    float* pooled = Aw + 16384;              // 32,768
    unsigned* hp_pair = (unsigned*)(pooled + 32768);  // 2,097,152 words
    // total ws: ~47.1 MB

    SrcPtrs S;
    for (int i = 0; i < 28; i++) S.p[i] = d_in[i];

    k_detect<<<1, 64, 0, stream>>>((const unsigned*)d_in[0], flag);
    k_convert<<<dim3(1152, 28), 256, 0, stream>>>(S, pf, flag);

    hipMemsetAsync(pooled, 0, BB * HDD * sizeof(float), stream);

    k_embed<<<BB * NN, 128, 0, stream>>>(xf, cw, cb, bg, bbt, bm, bv, h);
    k_aw<<<NN, 128, 0, stream>>>(wp, wm, Aw);

    for (int i = 0; i < LLY; i++) {
        k_hp<<<BB * NN / NPB, 128, 0, stream>>>(
            h, Wf + i * HDD * HDD, asrc + i * NHH * DHH, adst + i * NHH * DHH,
            hp_pair, s_buf, t_buf);
        k_attn<<<dim3(BB, 2), 256, 0, stream>>>(
            hp_pair, s_buf, t_buf, Aw, sa, ewa, lng + i * HDD, lnb + i * HDD, g);
        k_ffn<<<BB * NN / NPB, 256, 0, stream>>>(
            g, fw1 + i * HDD * FFD, fb1 + i * FFD, fw2 + i * FFD * HDD, fb2 + i * HDD, h);
    }

    k_norm<<<BB * NN, 64, 0, stream>>>(h, ng, nb, g);   // reuse g as hn
    k_proj<<<BB * NN / NPB, 128, 0, stream>>>(g, pw, pooled);
    k_head<<<BB, 64, 0, stream>>>(pooled, pb, hw1, hb1, hw2, hb2, d_out, flag);
}

// Round 3
// 458.480 us; speedup vs baseline: 2.4607x; 2.4607x over previous
//
#include <hip/hip_runtime.h>
#include <hip/hip_bf16.h>

typedef __hip_bfloat16 bf16;
typedef unsigned short u16;
typedef __attribute__((ext_vector_type(8))) short bfrag;   // 8 bf16 = 4 VGPR
typedef __attribute__((ext_vector_type(4))) float cfrag;   // 4 f32 acc

union BF { bfrag v; u16 u[8]; };
union CF { cfrag v; float f[4]; };

#define MFMA(a,b,c) __builtin_amdgcn_mfma_f32_16x16x32_bf16(a,b,c,0,0,0)

#define BB   256
#define NN   128
#define IND  9
#define HDD  128
#define NHH  8
#define DHH  16
#define LLY  4
#define OUTD 60
#define FFD  256
#define NPB  8

__device__ __forceinline__ float b2f(bf16 v){ return __bfloat162float(v); }
__device__ __forceinline__ float u2f(u16 u){ return __uint_as_float(((unsigned)u) << 16); }
__device__ __forceinline__ u16 f2bf_bits(float f){
    unsigned u = __float_as_uint(f);
    return (u16)((u + 0x7FFFu + ((u >> 16) & 1u)) >> 16);   // RNE
}
__device__ __forceinline__ float wave_sum(float v){
    #pragma unroll
    for (int m = 32; m; m >>= 1) v += __shfl_xor(v, m, 64);
    return v;
}

// ================= dtype detection (bf16 vs f32 inputs) =================
__global__ __launch_bounds__(64) void k_detect(const unsigned* __restrict__ xw, int* __restrict__ flag)
{
    int lane = threadIdx.x;
    int cnt = 0;
    for (int i = lane; i < 2048; i += 64) {
        unsigned lo = xw[i] & 0xFFFFu;
        float v = __uint_as_float(lo << 16);
        if (!(fabsf(v) < 32.f)) cnt++;
    }
    float c = wave_sum((float)cnt);
    if (lane == 0) *flag = (c < 64.f) ? 1 : 0;   // 1 = bf16, 0 = fp32
}

// ================= input -> fp32 conversion =================
struct SrcPtrs { const void* p[28]; };
__device__ const int CVT_SZ[28] = {
    294912,1152,128,128,128,128,128,65536,512,512,512,512,
    131072,1024,131072,512,128,128,16384,128,8192,64,3840,60,
    16384,16384,16384,16384};
__device__ const int CVT_OFF[28] = {
    0,294912,296064,296192,296320,296448,296576,296704,362240,362752,363264,363776,
    364288,495360,496384,627456,627968,628096,628224,644608,644736,652928,652992,656832,
    656896,673280,689664,706048};

__global__ __launch_bounds__(256) void k_convert(SrcPtrs S, float* __restrict__ dst,
                                                 const int* __restrict__ flag)
{
    int y = blockIdx.y;
    int sz = CVT_SZ[y];
    int idx = blockIdx.x * 256 + threadIdx.x;
    if (idx >= sz) return;
    float v;
    if (*flag) v = b2f(((const bf16*)S.p[y])[idx]);
    else       v = ((const float*)S.p[y])[idx];
    dst[CVT_OFF[y] + idx] = v;
}

// ================= weight transpose-pack to bf16 B^T layout =================
// dst[l][n][k] = bf16(src[l][k][n])
__global__ __launch_bounds__(256) void k_packT(const float* __restrict__ src, u16* __restrict__ dst,
                                               int K, int N)
{
    int l = blockIdx.y;
    int idx = blockIdx.x * 256 + threadIdx.x;
    if (idx >= K * N) return;
    int n = idx / K, k = idx - n * K;
    dst[l * K * N + idx] = f2bf_bits(src[l * K * N + k * N + n]);
}

// ================= masked edge bias -> bf16 =================
__global__ __launch_bounds__(256) void k_ewam(const float* __restrict__ ewa, const float* __restrict__ sa,
                                              u16* __restrict__ out)
{
    int idx = blockIdx.x * 256 + threadIdx.x;   // 16384
    out[idx] = f2bf_bits(sa[idx] > 0.f ? ewa[idx] : -1e30f);
}

// ================= embedding: conv1d(k=1) + eval BN + relu =================
__global__ __launch_bounds__(128) void k_embed(
    const float* __restrict__ xf, const float* __restrict__ cw, const float* __restrict__ cb,
    const float* __restrict__ bg, const float* __restrict__ bbt,
    const float* __restrict__ bm, const float* __restrict__ bv,
    float* __restrict__ h, u16* __restrict__ h16)
{
    int bn = blockIdx.x, d = threadIdx.x;
    __shared__ float xs[IND];
    if (d < IND) xs[d] = xf[bn * IND + d];
    __syncthreads();
    float acc = cb[d];
    #pragma unroll
    for (int k = 0; k < IND; k++) acc = fmaf(xs[k], cw[d * IND + k], acc);
    acc = (acc - bm[d]) * rsqrtf(bv[d] + 1e-5f) * bg[d] + bbt[d];
    acc = fmaxf(acc, 0.f);
    h[bn * HDD + d] = acc;
    h16[bn * HDD + d] = f2bf_bits(acc);
}

// ================= weak adjacency -> bf16 (row-normalized) =================
__global__ __launch_bounds__(128) void k_aw(
    const float* __restrict__ wp, const float* __restrict__ wm, u16* __restrict__ Aw16)
{
    int i = blockIdx.x, j = threadIdx.x;
    float v = wm[i * NN + j] / (1.f + __expf(-wp[i * NN + j]));
    __shared__ float red[2];
    float sm = wave_sum(v);
    if ((j & 63) == 0) red[j >> 6] = sm;
    __syncthreads();
    float tot = red[0] + red[1];
    Aw16[i * NN + j] = f2bf_bits(v / (tot + 1e-5f));
}

// ================= per-layer megakernel: hp GEMM + attention + FFN =================
// 1 block per graph b; 256 threads = 4 waves; wave wv owns rows wv*32..wv*32+31.
#define LDS_BYTES 80384
__global__ __launch_bounds__(256, 2) void k_layer(
    float* __restrict__ hg, u16* __restrict__ h16g,
    const u16* __restrict__ WT,                                    // [128 e][128 k]
    const float* __restrict__ asrc, const float* __restrict__ adst, // [128]
    const u16* __restrict__ Aw16,                                  // [128][128] A-layout
    const u16* __restrict__ ewam16,                                // [128][128] masked bias
    const float* __restrict__ lng, const float* __restrict__ lnb,
    const u16* __restrict__ w1T, const float* __restrict__ b1,     // [256][128], [256]
    const u16* __restrict__ w2T, const float* __restrict__ b2)     // [128][256], [128]
{
    extern __shared__ char smem[];
    u16* hpT    = (u16*)smem;                   // [128 dims][136] node-contiguous (B^T layout)
    u16* gbuf   = hpT + 128 * 136;              // [128 rows][136] (A layout)
    u16* hidb   = hpT;                          // alias: hpT dead after weak GEMM
    float* s_lds = (float*)(gbuf + 128 * 136);  // [8][128]
    float* t_lds = s_lds + 8 * 128;             // [8][128]
    float* lng_s = t_lds + 8 * 128;             // [128]
    float* lnb_s = lng_s + 128;                 // [128]
    float* b1_s  = lnb_s + 128;                 // [256]
    float* b2_s  = b1_s + 256;                  // [128]

    const int b = blockIdx.x;
    const int tid = threadIdx.x;
    const int lane = tid & 63, wv = tid >> 6;
    const int l15 = lane & 15, kg = lane >> 4;
    const int base = b * 128;

    if (tid < 128) { lng_s[tid] = lng[tid]; lnb_s[tid] = lnb[tid]; b2_s[tid] = b2[tid]; }
    b1_s[tid] = b1[tid];

    // ---------- Phase 1: hp = h @ W  (M=128,N=128,K=128), write hpT bf16 ----------
    CF acc[2][8];
    #pragma unroll
    for (int mt = 0; mt < 2; mt++)
        #pragma unroll
        for (int nt = 0; nt < 8; nt++)
            #pragma unroll
            for (int r = 0; r < 4; r++) acc[mt][nt].f[r] = 0.f;

    #pragma unroll
    for (int kk = 0; kk < 4; kk++) {
        bfrag af[2];
        #pragma unroll
        for (int mt = 0; mt < 2; mt++)
            af[mt] = *(const bfrag*)&h16g[(base + wv*32 + mt*16 + l15) * 128 + kk*32 + kg*8];
        #pragma unroll
        for (int nt = 0; nt < 8; nt++) {
            bfrag bw = *(const bfrag*)&WT[(nt*16 + l15) * 128 + kk*32 + kg*8];
            #pragma unroll
            for (int mt = 0; mt < 2; mt++)
                acc[mt][nt].v = MFMA(af[mt], bw, acc[mt][nt].v);
        }
    }
    #pragma unroll
    for (int mt = 0; mt < 2; mt++)
        #pragma unroll
        for (int nt = 0; nt < 8; nt++) {
            int col = nt*16 + l15;                       // dim e
            #pragma unroll
            for (int rp = 0; rp < 2; rp++) {
                int row = wv*32 + mt*16 + kg*4 + rp*2;   // node
                unsigned pk = (unsigned)f2bf_bits(acc[mt][nt].f[rp*2]) |
                              ((unsigned)f2bf_bits(acc[mt][nt].f[rp*2+1]) << 16);
                *(unsigned*)&hpT[col * 136 + row] = pk;  // row even, stride even -> aligned
            }
        }
    __syncthreads();

    // ---------- Phase 2: s,t head scores ----------
    {
        int node = tid & 127, which = tid >> 7;
        const float* av = which ? adst : asrc;
        float* dst = which ? t_lds : s_lds;
        #pragma unroll
        for (int h = 0; h < 8; h++) {
            float a = 0.f;
            #pragma unroll
            for (int d = 0; d < 16; d++)
                a = fmaf(u2f(hpT[(h*16 + d) * 136 + node]), av[h*16 + d], a);
            dst[h * 128 + node] = a;
        }
    }
    __syncthreads();

    // ---------- Phase 3: per-head softmax (in A-frag layout) + strong MFMA ----------
    CF accS[2][8];
    #pragma unroll
    for (int mt = 0; mt < 2; mt++)
        #pragma unroll
        for (int nt = 0; nt < 8; nt++)
            #pragma unroll
            for (int r = 0; r < 4; r++) accS[mt][nt].f[r] = 0.f;

    #pragma unroll 1
    for (int h = 0; h < 8; h++) {
        bfrag hb[4];
        #pragma unroll
        for (int kk = 0; kk < 4; kk++)
            hb[kk] = *(const bfrag*)&hpT[(h*16 + l15) * 136 + kk*32 + kg*8];
        #pragma unroll 1
        for (int mt = 0; mt < 2; mt++) {
            int row = wv*32 + mt*16 + l15;               // node i (A-frag row)
            float sA = s_lds[h * 128 + row];
            float pv[4][8];
            float mx = -1e30f;
            #pragma unroll
            for (int kk = 0; kk < 4; kk++) {
                const float* tp = &t_lds[h * 128 + kk*32 + kg*8];
                BF ew; ew.v = *(const bfrag*)&ewam16[row * 128 + kk*32 + kg*8];
                #pragma unroll
                for (int j = 0; j < 8; j++) {
                    float v = sA + tp[j];
                    v = v > 0.f ? v : 0.2f * v;          // leaky_relu(0.2)
                    v += u2f(ew.u[j]);                   // + bias, or -1e30 if masked
                    pv[kk][j] = v;
                    mx = fmaxf(mx, v);
                }
            }
            mx = fmaxf(mx, __shfl_xor(mx, 16, 64));
            mx = fmaxf(mx, __shfl_xor(mx, 32, 64));      // row-max over all 128 j
            float sm = 0.f;
            #pragma unroll
            for (int kk = 0; kk < 4; kk++)
                #pragma unroll
                for (int j = 0; j < 8; j++) {
                    float p = __expf(pv[kk][j] - mx);    // masked -> exp(-inf)=0
                    pv[kk][j] = p; sm += p;
                }
            sm += __shfl_xor(sm, 16, 64);
            sm += __shfl_xor(sm, 32, 64);
            float inv = 1.f / sm;
            #pragma unroll
            for (int kk = 0; kk < 4; kk++) {
                BF pb;
                #pragma unroll
                for (int j = 0; j < 8; j++) pb.u[j] = f2bf_bits(pv[kk][j] * inv);
                accS[mt][h].v = MFMA(pb.v, hb[kk], accS[mt][h].v);
            }
        }
    }

    // ---------- Phase 4: weak = Aw @ hp ----------
    CF accW[2][8];
    #pragma unroll
    for (int mt = 0; mt < 2; mt++)
        #pragma unroll
        for (int nt = 0; nt < 8; nt++)
            #pragma unroll
            for (int r = 0; r < 4; r++) accW[mt][nt].f[r] = 0.f;

    #pragma unroll
    for (int kk = 0; kk < 4; kk++) {
        bfrag awf[2];
        #pragma unroll
        for (int mt = 0; mt < 2; mt++)
            awf[mt] = *(const bfrag*)&Aw16[(wv*32 + mt*16 + l15) * 128 + kk*32 + kg*8];
        #pragma unroll
        for (int nt = 0; nt < 8; nt++) {
            bfrag hb2 = *(const bfrag*)&hpT[(nt*16 + l15) * 136 + kk*32 + kg*8];
            #pragma unroll
            for (int mt = 0; mt < 2; mt++)
                accW[mt][nt].v = MFMA(awf[mt], hb2, accW[mt][nt].v);
        }
    }

    // ---------- Phase 5: g = relu(0.6 s + 0.4 w), LayerNorm, write gbuf bf16 ----------
    float gv[2][8][4];
    #pragma unroll
    for (int mt = 0; mt < 2; mt++)
        #pragma unroll
        for (int nt = 0; nt < 8; nt++)
            #pragma unroll
            for (int r = 0; r < 4; r++)
                gv[mt][nt][r] = fmaxf(0.6f * accS[mt][nt].f[r] + 0.4f * accW[mt][nt].f[r], 0.f);

    #pragma unroll
    for (int mt = 0; mt < 2; mt++)
        #pragma unroll
        for (int r = 0; r < 4; r++) {
            float s1 = 0.f, s2 = 0.f;
            #pragma unroll
            for (int nt = 0; nt < 8; nt++) { float x = gv[mt][nt][r]; s1 += x; s2 = fmaf(x, x, s2); }
            #pragma unroll
            for (int m = 1; m <= 8; m <<= 1) { s1 += __shfl_xor(s1, m, 64); s2 += __shfl_xor(s2, m, 64); }
            float mu = s1 * (1.f / 128.f);
            float var = s2 * (1.f / 128.f) - mu * mu;
            float rs = rsqrtf(fmaxf(var, 0.f) + 1e-5f);
            int row = wv*32 + mt*16 + kg*4 + r;
            #pragma unroll
            for (int nt = 0; nt < 8; nt++) {
                int col = nt*16 + l15;
                float gn = fmaf((gv[mt][nt][r] - mu) * rs, lng_s[col], lnb_s[col]);
                gbuf[row * 136 + col] = f2bf_bits(gn);
            }
        }
    __syncthreads();

    // ---------- Phase 6: FFN in two N-halves through LDS, acc2 held across ----------
    CF acc2[2][8];
    #pragma unroll
    for (int mt = 0; mt < 2; mt++)
        #pragma unroll
        for (int nt = 0; nt < 8; nt++)
            #pragma unroll
            for (int r = 0; r < 4; r++) acc2[mt][nt].f[r] = 0.f;

    #pragma unroll 1
    for (int nh = 0; nh < 2; nh++) {
        CF a1[2][8];
        #pragma unroll
        for (int mt = 0; mt < 2; mt++)
            #pragma unroll
            for (int nt = 0; nt < 8; nt++)
                #pragma unroll
                for (int r = 0; r < 4; r++) a1[mt][nt].f[r] = 0.f;
        #pragma unroll
        for (int kk = 0; kk < 4; kk++) {
            bfrag gf[2];
            #pragma unroll
            for (int mt = 0; mt < 2; mt++)
                gf[mt] = *(const bfrag*)&gbuf[(wv*32 + mt*16 + l15) * 136 + kk*32 + kg*8];
            #pragma unroll
            for (int nt = 0; nt < 8; nt++) {
                bfrag wf = *(const bfrag*)&w1T[(nh*128 + nt*16 + l15) * 128 + kk*32 + kg*8];
                #pragma unroll
                for (int mt = 0; mt < 2; mt++)
                    a1[mt][nt].v = MFMA(gf[mt], wf, a1[mt][nt].v);
            }
        }
        __syncthreads();   // prior hidb readers (phase4 hpT / previous nh FFN2) done
        #pragma unroll
        for (int mt = 0; mt < 2; mt++)
            #pragma unroll
            for (int nt = 0; nt < 8; nt++) {
                int col = nt*16 + l15;
                #pragma unroll
                for (int r = 0; r < 4; r++) {
                    int row = wv*32 + mt*16 + kg*4 + r;
                    float hv = a1[mt][nt].f[r] + b1_s[nh*128 + col];
                    hidb[row * 136 + col] = f2bf_bits(fmaxf(hv, 0.f));
                }
            }
        __syncthreads();
        #pragma unroll
        for (int kk = 0; kk < 4; kk++) {
            bfrag hf[2];
            #pragma unroll
            for (int mt = 0; mt < 2; mt++)
                hf[mt] = *(const bfrag*)&hidb[(wv*32 + mt*16 + l15) * 136 + kk*32 + kg*8];
            #pragma unroll
            for (int nt = 0; nt < 8; nt++) {
                bfrag wf = *(const bfrag*)&w2T[(nt*16 + l15) * 256 + nh*128 + kk*32 + kg*8];
                #pragma unroll
                for (int mt = 0; mt < 2; mt++)
                    acc2[mt][nt].v = MFMA(hf[mt], wf, acc2[mt][nt].v);
            }
        }
    }

    // ---------- Epilogue: + b2 + residual; write h f32 + bf16 ----------
    #pragma unroll
    for (int mt = 0; mt < 2; mt++)
        #pragma unroll
        for (int nt = 0; nt < 8; nt++) {
            int col = nt*16 + l15;
            #pragma unroll
            for (int r = 0; r < 4; r++) {
                int row = wv*32 + mt*16 + kg*4 + r;
                int gi = (base + row) * 128 + col;
                float hv = acc2[mt][nt].f[r] + b2_s[col] + hg[gi];
                hg[gi] = hv;
                h16g[gi] = f2bf_bits(hv);
            }
        }
}

// ================= final LN =================
__global__ __launch_bounds__(64) void k_norm(
    const float* __restrict__ h, const float* __restrict__ ng, const float* __restrict__ nb,
    float* __restrict__ hn)
{
    int bn = blockIdx.x, lane = threadIdx.x;
    float v0 = h[bn * HDD + lane], v1 = h[bn * HDD + lane + 64];
    float mean = wave_sum(v0 + v1) * (1.f / HDD);
    float d0 = v0 - mean, d1 = v1 - mean;
    float var = wave_sum(d0 * d0 + d1 * d1) * (1.f / HDD);
    float rs = rsqrtf(var + 1e-5f);
    hn[bn * HDD + lane]      = fmaf(d0 * rs, ng[lane], nb[lane]);
    hn[bn * HDD + lane + 64] = fmaf(d1 * rs, ng[lane + 64], nb[lane + 64]);
}

// ================= proj + partial node-sum =================
__global__ __launch_bounds__(128) void k_proj(
    const float* __restrict__ hn, const float* __restrict__ pw, float* __restrict__ pooled)
{
    int base = blockIdx.x * NPB;
    int e = threadIdx.x;
    float acc[NPB];
    #pragma unroll
    for (int n = 0; n < NPB; n++) acc[n] = 0.f;
    for (int k = 0; k < HDD; k += 4) {
        float w0 = pw[(k + 0) * HDD + e];
        float wA = pw[(k + 1) * HDD + e];
        float wB = pw[(k + 2) * HDD + e];
        float wC = pw[(k + 3) * HDD + e];
        #pragma unroll
        for (int n = 0; n < NPB; n++) {
            const float4 hv = *(const float4*)&hn[(base + n) * HDD + k];
            acc[n] = fmaf(hv.x, w0, acc[n]);
            acc[n] = fmaf(hv.y, wA, acc[n]);
            acc[n] = fmaf(hv.z, wB, acc[n]);
            acc[n] = fmaf(hv.w, wC, acc[n]);
        }
    }
    float tot = 0.f;
    #pragma unroll
    for (int n = 0; n < NPB; n++) tot += acc[n];
    int b = base / NN;
    atomicAdd(&pooled[b * HDD + e], tot);
}

// ================= head (dtype-flag-aware output) =================
__global__ __launch_bounds__(64) void k_head(
    const float* __restrict__ pooled, const float* __restrict__ pb,
    const float* __restrict__ w1, const float* __restrict__ b1,
    const float* __restrict__ w2, const float* __restrict__ b2,
    void* __restrict__ outv, const int* __restrict__ flag)
{
    int b = blockIdx.x, t = threadIdx.x;
    __shared__ float pl[HDD], r1[64];
    pl[t]      = pooled[b * HDD + t]      * (1.f / NN) + pb[t];
    pl[t + 64] = pooled[b * HDD + t + 64] * (1.f / NN) + pb[t + 64];
    __syncthreads();
    float acc = b1[t];
    for (int k = 0; k < HDD; k++) acc = fmaf(pl[k], w1[k * 64 + t], acc);
    r1[t] = fmaxf(acc, 0.f);
    __syncthreads();
    if (t < OUTD) {
        float a = b2[t];
        for (int k = 0; k < 64; k++) a = fmaf(r1[k], w2[k * OUTD + t], a);
        if (*flag) ((bf16*)outv)[b * OUTD + t] = __float2bfloat16(a);
        else       ((float*)outv)[b * OUTD + t] = a;
    }
}

extern "C" void kernel_launch(void* const* d_in, const int* in_sizes, int n_in,
                              void* d_out, int out_size, void* d_ws, size_t ws_size,
                              hipStream_t stream)
{
    float* ws = (float*)d_ws;
    float* pf = ws;                               // converted fp32 params [0..722432)
    const float* xf   = pf + 0;
    const float* cw   = pf + 294912;
    const float* cb   = pf + 296064;
    const float* bg   = pf + 296192;
    const float* bbt  = pf + 296320;
    const float* bm   = pf + 296448;
    const float* bv   = pf + 296576;
    const float* Wf   = pf + 296704;
    const float* asrcf= pf + 362240;
    const float* adstf= pf + 362752;
    const float* lng  = pf + 363264;
    const float* lnb  = pf + 363776;
    const float* fw1  = pf + 364288;
    const float* fb1  = pf + 495360;
    const float* fw2  = pf + 496384;
    const float* fb2  = pf + 627456;
    const float* ng   = pf + 627968;
    const float* nb   = pf + 628096;
    const float* pw   = pf + 628224;
    const float* pb   = pf + 644608;
    const float* hw1  = pf + 644736;
    const float* hb1  = pf + 652928;
    const float* hw2  = pf + 652992;
    const float* hb2  = pf + 656832;
    const float* sa   = pf + 656896;
    const float* wm   = pf + 673280;
    const float* wp   = pf + 689664;
    const float* ewa  = pf + 706048;

    int*   flag   = (int*)(ws + 722432);
    float* h      = ws + 722448;                  // 4,194,304 f32
    float* hn     = h + 4194304;                  // 4,194,304 f32
    float* pooled = hn + 4194304;                 // 32,768 f32
    u16* h16    = (u16*)(pooled + 32768);         // 4,194,304 u16
    u16* WT16   = h16 + 4194304;                  // 4*128*128
    u16* w1T16  = WT16 + 65536;                   // 4*256*128
    u16* w2T16  = w1T16 + 131072;                 // 4*128*256
    u16* Aw16   = w2T16 + 131072;                 // 128*128
    u16* ewam16 = Aw16 + 16384;                   // 128*128
    // total ~45.7 MB

    hipFuncSetAttribute((const void*)k_layer,
                        hipFuncAttributeMaxDynamicSharedMemorySize, LDS_BYTES);

    SrcPtrs S;
    for (int i = 0; i < 28; i++) S.p[i] = d_in[i];

    k_detect<<<1, 64, 0, stream>>>((const unsigned*)d_in[0], flag);
    k_convert<<<dim3(1152, 28), 256, 0, stream>>>(S, pf, flag);

    hipMemsetAsync(pooled, 0, BB * HDD * sizeof(float), stream);

    k_packT<<<dim3(64, LLY), 256, 0, stream>>>(Wf,  WT16,  128, 128);
    k_packT<<<dim3(128, LLY), 256, 0, stream>>>(fw1, w1T16, 128, 256);
    k_packT<<<dim3(128, LLY), 256, 0, stream>>>(fw2, w2T16, 256, 128);
    k_ewam<<<64, 256, 0, stream>>>(ewa, sa, ewam16);
    k_aw<<<NN, 128, 0, stream>>>(wp, wm, Aw16);
    k_embed<<<BB * NN, 128, 0, stream>>>(xf, cw, cb, bg, bbt, bm, bv, h, h16);

    for (int i = 0; i < LLY; i++) {
        k_layer<<<BB, 256, LDS_BYTES, stream>>>(
            h, h16,
            WT16 + i * 16384, asrcf + i * 128, adstf + i * 128,
            Aw16, ewam16,
            lng + i * 128, lnb + i * 128,
            w1T16 + i * 32768, fb1 + i * 256,
            w2T16 + i * 32768, fb2 + i * 128);
    }

    k_norm<<<BB * NN, 64, 0, stream>>>(h, ng, nb, hn);
    k_proj<<<BB * NN / NPB, 128, 0, stream>>>(hn, pw, pooled);
    k_head<<<BB, 64, 0, stream>>>(pooled, pb, hw1, hb1, hw2, hb2, d_out, flag);
}

// Round 4
// 441.325 us; speedup vs baseline: 2.5564x; 1.0389x over previous
//
#include <hip/hip_runtime.h>
#include <hip/hip_bf16.h>

typedef __hip_bfloat16 bf16;
typedef unsigned short u16;
typedef __attribute__((ext_vector_type(8))) short bfrag;   // 8 bf16 = 4 VGPR
typedef __attribute__((ext_vector_type(4))) float cfrag;   // 4 f32 acc

union BF { bfrag v; u16 u[8]; };
union CF { cfrag v; float f[4]; };

#define MFMA(a,b,c) __builtin_amdgcn_mfma_f32_16x16x32_bf16(a,b,c,0,0,0)

#define BB   256
#define NN   128
#define IND  9
#define HDD  128
#define NHH  8
#define DHH  16
#define LLY  4
#define OUTD 60
#define FFD  256

__device__ __forceinline__ float b2f(bf16 v){ return __bfloat162float(v); }
__device__ __forceinline__ float u2f(u16 u){ return __uint_as_float(((unsigned)u) << 16); }
__device__ __forceinline__ u16 f2bf_bits(float f){
    unsigned u = __float_as_uint(f);
    return (u16)((u + 0x7FFFu + ((u >> 16) & 1u)) >> 16);   // RNE
}
__device__ __forceinline__ float wave_sum(float v){
    #pragma unroll
    for (int m = 32; m; m >>= 1) v += __shfl_xor(v, m, 64);
    return v;
}

// ================= dtype detection (bf16 vs f32 inputs) =================
__global__ __launch_bounds__(64) void k_detect(const unsigned* __restrict__ xw, int* __restrict__ flag)
{
    int lane = threadIdx.x;
    int cnt = 0;
    for (int i = lane; i < 2048; i += 64) {
        unsigned lo = xw[i] & 0xFFFFu;
        float v = __uint_as_float(lo << 16);
        if (!(fabsf(v) < 32.f)) cnt++;
    }
    float c = wave_sum((float)cnt);
    if (lane == 0) *flag = (c < 64.f) ? 1 : 0;   // 1 = bf16, 0 = fp32
}

// ================= input -> fp32 conversion =================
struct SrcPtrs { const void* p[28]; };
__device__ const int CVT_SZ[28] = {
    294912,1152,128,128,128,128,128,65536,512,512,512,512,
    131072,1024,131072,512,128,128,16384,128,8192,64,3840,60,
    16384,16384,16384,16384};
__device__ const int CVT_OFF[28] = {
    0,294912,296064,296192,296320,296448,296576,296704,362240,362752,363264,363776,
    364288,495360,496384,627456,627968,628096,628224,644608,644736,652928,652992,656832,
    656896,673280,689664,706048};

__global__ __launch_bounds__(256) void k_convert(SrcPtrs S, float* __restrict__ dst,
                                                 const int* __restrict__ flag)
{
    int y = blockIdx.y;
    int sz = CVT_SZ[y];
    int idx = blockIdx.x * 256 + threadIdx.x;
    if (idx >= sz) return;
    float v;
    if (*flag) v = b2f(((const bf16*)S.p[y])[idx]);
    else       v = ((const float*)S.p[y])[idx];
    dst[CVT_OFF[y] + idx] = v;
}

// ================= fused weight transpose-pack + masked edge bias =================
__global__ __launch_bounds__(256) void k_pack(
    const float* __restrict__ Wf, const float* __restrict__ fw1, const float* __restrict__ fw2,
    const float* __restrict__ ewa, const float* __restrict__ sa,
    u16* __restrict__ WT, u16* __restrict__ w1T, u16* __restrict__ w2T, u16* __restrict__ ewam)
{
    int idx = blockIdx.x * 256 + threadIdx.x;
    if (idx < 65536) {                         // WT[l][n(128)][k(128)] <- Wf[l][k][n]
        int l = idx >> 14, r = idx & 16383;
        int n = r >> 7, k = r & 127;
        WT[idx] = f2bf_bits(Wf[(l << 14) + k * 128 + n]);
    } else if (idx < 65536 + 131072) {         // w1T[l][n(256)][k(128)] <- fw1[l][k][n]
        int j = idx - 65536;
        int l = j >> 15, r = j & 32767;
        int n = r >> 7, k = r & 127;
        w1T[j] = f2bf_bits(fw1[(l << 15) + k * 256 + n]);
    } else if (idx < 65536 + 262144) {         // w2T[l][n(128)][k(256)] <- fw2[l][k][n]
        int j = idx - 65536 - 131072;
        int l = j >> 15, r = j & 32767;
        int n = r >> 8, k = r & 255;
        w2T[j] = f2bf_bits(fw2[(l << 15) + k * 128 + n]);
    } else if (idx < 65536 + 262144 + 16384) { // ewam
        int j = idx - 65536 - 262144;
        ewam[j] = f2bf_bits(sa[j] > 0.f ? ewa[j] : -1e30f);
    }
}

// ================= embedding: conv1d(k=1) + eval BN + relu =================
__global__ __launch_bounds__(256) void k_embed(
    const float* __restrict__ xf, const float* __restrict__ cw, const float* __restrict__ cb,
    const float* __restrict__ bg, const float* __restrict__ bbt,
    const float* __restrict__ bm, const float* __restrict__ bv,
    float* __restrict__ h, u16* __restrict__ h16)
{
    int b = blockIdx.x, tid = threadIdx.x;
    int d = tid & 127, nh = tid >> 7;
    float wreg[IND];
    #pragma unroll
    for (int k = 0; k < IND; k++) wreg[k] = cw[d * IND + k];
    float scale = rsqrtf(bv[d] + 1e-5f) * bg[d];
    float bias  = bbt[d] - bm[d] * scale;
    float cbd   = cb[d];
    for (int it = 0; it < 64; it++) {
        int bn = b * NN + it * 2 + nh;          // wave-uniform
        float acc = cbd;
        #pragma unroll
        for (int k = 0; k < IND; k++) acc = fmaf(xf[bn * IND + k], wreg[k], acc);
        acc = fmaxf(fmaf(acc, scale, bias), 0.f);
        h[bn * HDD + d] = acc;
        h16[bn * HDD + d] = f2bf_bits(acc);
    }
}

// ================= weak adjacency -> bf16 (row-normalized) =================
__global__ __launch_bounds__(128) void k_aw(
    const float* __restrict__ wp, const float* __restrict__ wm, u16* __restrict__ Aw16)
{
    int i = blockIdx.x, j = threadIdx.x;
    float v = wm[i * NN + j] / (1.f + __expf(-wp[i * NN + j]));
    __shared__ float red[2];
    float sm = wave_sum(v);
    if ((j & 63) == 0) red[j >> 6] = sm;
    __syncthreads();
    float tot = red[0] + red[1];
    Aw16[i * NN + j] = f2bf_bits(v / (tot + 1e-5f));
}

// ================= per-layer megakernel: 512 threads = 8 waves, 16 rows/wave =================
#define LDS_BYTES 80384
__global__ __launch_bounds__(512, 2) void k_layer(
    float* __restrict__ hg, u16* __restrict__ h16g,
    const u16* __restrict__ WT,
    const float* __restrict__ asrc, const float* __restrict__ adst,
    const u16* __restrict__ Aw16, const u16* __restrict__ ewam16,
    const float* __restrict__ lng, const float* __restrict__ lnb,
    const u16* __restrict__ w1T, const float* __restrict__ b1,
    const u16* __restrict__ w2T, const float* __restrict__ b2)
{
    extern __shared__ char smem[];
    u16* hpT    = (u16*)smem;                   // [128 dims][136 nodes]
    u16* gbuf   = hpT + 128 * 136;              // [128 rows][136]
    u16* hidb   = hpT;                          // alias: hpT dead after phase 4
    float* s_lds = (float*)(gbuf + 128 * 136);  // [8][128]
    float* t_lds = s_lds + 8 * 128;             // [8][128]
    float* lng_s = t_lds + 8 * 128;
    float* lnb_s = lng_s + 128;
    float* b1_s  = lnb_s + 128;                 // [256]
    float* b2_s  = b1_s + 256;

    const int b = blockIdx.x;
    const int tid = threadIdx.x;
    const int lane = tid & 63, wv = tid >> 6;
    const int l15 = lane & 15, kg = lane >> 4;
    const int wrow = wv * 16;
    const int base = b * NN;

    if (tid < 128) { lng_s[tid] = lng[tid]; lnb_s[tid] = lnb[tid]; b2_s[tid] = b2[tid]; }
    if (tid < 256) b1_s[tid] = b1[tid];

    // ---------- Phase 1: hp = h @ W, write hpT bf16 ----------
    CF acc[8];
    #pragma unroll
    for (int nt = 0; nt < 8; nt++)
        #pragma unroll
        for (int r = 0; r < 4; r++) acc[nt].f[r] = 0.f;

    #pragma unroll
    for (int kk = 0; kk < 4; kk++) {
        bfrag af = *(const bfrag*)&h16g[(base + wrow + l15) * 128 + kk*32 + kg*8];
        #pragma unroll
        for (int nt = 0; nt < 8; nt++) {
            bfrag bw = *(const bfrag*)&WT[(nt*16 + l15) * 128 + kk*32 + kg*8];
            acc[nt].v = MFMA(af, bw, acc[nt].v);
        }
    }
    #pragma unroll
    for (int nt = 0; nt < 8; nt++) {
        int col = nt*16 + l15;
        #pragma unroll
        for (int rp = 0; rp < 2; rp++) {
            int row = wrow + kg*4 + rp*2;
            unsigned pk = (unsigned)f2bf_bits(acc[nt].f[rp*2]) |
                          ((unsigned)f2bf_bits(acc[nt].f[rp*2+1]) << 16);
            *(unsigned*)&hpT[col * 136 + row] = pk;
        }
    }
    __syncthreads();

    // ---------- Phase 2: s,t head scores (512 threads = node x {s,t} x head-half) ----------
    {
        int node = tid & 127, sel = tid >> 7;
        int which = sel & 1, hb4 = (sel >> 1) * 4;
        const float* av = which ? adst : asrc;
        float* dst = which ? t_lds : s_lds;
        #pragma unroll
        for (int hh = 0; hh < 4; hh++) {
            int h = hb4 + hh;
            float a = 0.f;
            #pragma unroll
            for (int d = 0; d < 16; d++)
                a = fmaf(u2f(hpT[(h*16 + d) * 136 + node]), av[h*16 + d], a);
            dst[h * 128 + node] = a;
        }
    }
    __syncthreads();

    // ---------- Phase 3: softmax in A-frag layout + strong MFMA ----------
    CF accS[8];
    #pragma unroll
    for (int nt = 0; nt < 8; nt++)
        #pragma unroll
        for (int r = 0; r < 4; r++) accS[nt].f[r] = 0.f;

    const int arow = wrow + l15;                 // this lane's A-frag row (node i)
    #pragma unroll 1
    for (int h = 0; h < 8; h++) {
        bfrag hb[4];
        #pragma unroll
        for (int kk = 0; kk < 4; kk++)
            hb[kk] = *(const bfrag*)&hpT[(h*16 + l15) * 136 + kk*32 + kg*8];
        float sA = s_lds[h * 128 + arow];
        float pv[4][8];
        float mx = -1e30f;
        #pragma unroll
        for (int kk = 0; kk < 4; kk++) {
            const float* tp = &t_lds[h * 128 + kk*32 + kg*8];
            BF ew; ew.v = *(const bfrag*)&ewam16[arow * 128 + kk*32 + kg*8];
            #pragma unroll
            for (int j = 0; j < 8; j++) {
                float v = sA + tp[j];
                v = v > 0.f ? v : 0.2f * v;      // leaky_relu(0.2)
                v += u2f(ew.u[j]);               // + bias, or -1e30 if masked
                pv[kk][j] = v;
                mx = fmaxf(mx, v);
            }
        }
        mx = fmaxf(mx, __shfl_xor(mx, 16, 64));
        mx = fmaxf(mx, __shfl_xor(mx, 32, 64));
        float sm = 0.f;
        #pragma unroll
        for (int kk = 0; kk < 4; kk++)
            #pragma unroll
            for (int j = 0; j < 8; j++) {
                float p = __expf(pv[kk][j] - mx);
                pv[kk][j] = p; sm += p;
            }
        sm += __shfl_xor(sm, 16, 64);
        sm += __shfl_xor(sm, 32, 64);
        float inv = 1.f / sm;
        #pragma unroll
        for (int kk = 0; kk < 4; kk++) {
            BF pb;
            #pragma unroll
            for (int j = 0; j < 8; j++) pb.u[j] = f2bf_bits(pv[kk][j] * inv);
            accS[h].v = MFMA(pb.v, hb[kk], accS[h].v);
        }
    }

    // ---------- Phase 4: weak = Aw @ hp ----------
    CF accW[8];
    #pragma unroll
    for (int nt = 0; nt < 8; nt++)
        #pragma unroll
        for (int r = 0; r < 4; r++) accW[nt].f[r] = 0.f;

    #pragma unroll
    for (int kk = 0; kk < 4; kk++) {
        bfrag awf = *(const bfrag*)&Aw16[(wrow + l15) * 128 + kk*32 + kg*8];
        #pragma unroll
        for (int nt = 0; nt < 8; nt++) {
            bfrag hb2 = *(const bfrag*)&hpT[(nt*16 + l15) * 136 + kk*32 + kg*8];
            accW[nt].v = MFMA(awf, hb2, accW[nt].v);
        }
    }

    // ---------- Phase 5: g = relu(0.6 s + 0.4 w), LN, write gbuf ----------
    float gv[8][4];
    #pragma unroll
    for (int nt = 0; nt < 8; nt++)
        #pragma unroll
        for (int r = 0; r < 4; r++)
            gv[nt][r] = fmaxf(0.6f * accS[nt].f[r] + 0.4f * accW[nt].f[r], 0.f);

    #pragma unroll
    for (int r = 0; r < 4; r++) {
        float s1 = 0.f, s2 = 0.f;
        #pragma unroll
        for (int nt = 0; nt < 8; nt++) { float x = gv[nt][r]; s1 += x; s2 = fmaf(x, x, s2); }
        #pragma unroll
        for (int m = 1; m <= 8; m <<= 1) { s1 += __shfl_xor(s1, m, 64); s2 += __shfl_xor(s2, m, 64); }
        float mu = s1 * (1.f / 128.f);
        float var = s2 * (1.f / 128.f) - mu * mu;
        float rs = rsqrtf(fmaxf(var, 0.f) + 1e-5f);
        int row = wrow + kg*4 + r;
        #pragma unroll
        for (int nt = 0; nt < 8; nt++) {
            int col = nt*16 + l15;
            float gn = fmaf((gv[nt][r] - mu) * rs, lng_s[col], lnb_s[col]);
            gbuf[row * 136 + col] = f2bf_bits(gn);
        }
    }
    __syncthreads();

    // ---------- Phase 6: FFN, two N-halves through LDS ----------
    CF acc2[8];
    #pragma unroll
    for (int nt = 0; nt < 8; nt++)
        #pragma unroll
        for (int r = 0; r < 4; r++) acc2[nt].f[r] = 0.f;

    #pragma unroll 1
    for (int nh = 0; nh < 2; nh++) {
        CF a1[8];
        #pragma unroll
        for (int nt = 0; nt < 8; nt++)
            #pragma unroll
            for (int r = 0; r < 4; r++) a1[nt].f[r] = 0.f;
        #pragma unroll
        for (int kk = 0; kk < 4; kk++) {
            bfrag gf = *(const bfrag*)&gbuf[(wrow + l15) * 136 + kk*32 + kg*8];
            #pragma unroll
            for (int nt = 0; nt < 8; nt++) {
                bfrag wf = *(const bfrag*)&w1T[(nh*128 + nt*16 + l15) * 128 + kk*32 + kg*8];
                a1[nt].v = MFMA(gf, wf, a1[nt].v);
            }
        }
        __syncthreads();   // prior hidb/hpT readers done
        #pragma unroll
        for (int nt = 0; nt < 8; nt++) {
            int col = nt*16 + l15;
            #pragma unroll
            for (int r = 0; r < 4; r++) {
                int row = wrow + kg*4 + r;
                float hv = a1[nt].f[r] + b1_s[nh*128 + col];
                hidb[row * 136 + col] = f2bf_bits(fmaxf(hv, 0.f));
            }
        }
        __syncthreads();
        #pragma unroll
        for (int kk = 0; kk < 4; kk++) {
            bfrag hf = *(const bfrag*)&hidb[(wrow + l15) * 136 + kk*32 + kg*8];
            #pragma unroll
            for (int nt = 0; nt < 8; nt++) {
                bfrag wf = *(const bfrag*)&w2T[(nt*16 + l15) * 256 + nh*128 + kk*32 + kg*8];
                acc2[nt].v = MFMA(hf, wf, acc2[nt].v);
            }
        }
    }

    // ---------- Epilogue: + b2 + residual ----------
    #pragma unroll
    for (int nt = 0; nt < 8; nt++) {
        int col = nt*16 + l15;
        #pragma unroll
        for (int r = 0; r < 4; r++) {
            int row = wrow + kg*4 + r;
            int gi = (base + row) * HDD + col;
            float hv = acc2[nt].f[r] + b2_s[col] + hg[gi];
            hg[gi] = hv;
            h16g[gi] = f2bf_bits(hv);
        }
    }
}

// ================= fused final: LN + proj + mean-pool + head =================
// mean-pool commutes with the affine proj => proj once per graph, not per node.
__global__ __launch_bounds__(256) void k_final(
    const float* __restrict__ h, const float* __restrict__ ng, const float* __restrict__ nb,
    const float* __restrict__ pw, const float* __restrict__ pb,
    const float* __restrict__ hw1, const float* __restrict__ hb1,
    const float* __restrict__ hw2, const float* __restrict__ hb2,
    void* __restrict__ outv, const int* __restrict__ flag)
{
    int b = blockIdx.x, tid = threadIdx.x, lane = tid & 63, wv = tid >> 6;
    __shared__ float psum[4][128];
    __shared__ float ph[2][128];
    __shared__ float pooled[128];
    __shared__ float hq[4][64];
    __shared__ float r1[64];

    float g0 = ng[lane], g1 = ng[lane + 64];
    float nb0 = nb[lane], nb1 = nb[lane + 64];
    float a0 = 0.f, a1 = 0.f;
    for (int it = 0; it < 32; it++) {
        int bn = b * NN + wv * 32 + it;
        float v0 = h[bn * HDD + lane], v1 = h[bn * HDD + lane + 64];
        float mean = wave_sum(v0 + v1) * (1.f / 128.f);
        float d0 = v0 - mean, d1 = v1 - mean;
        float var = wave_sum(d0 * d0 + d1 * d1) * (1.f / 128.f);
        float rs = rsqrtf(var + 1e-5f);
        a0 += fmaf(d0 * rs, g0, nb0);
        a1 += fmaf(d1 * rs, g1, nb1);
    }
    psum[wv][lane] = a0; psum[wv][lane + 64] = a1;
    __syncthreads();

    int e = tid & 127, kh = tid >> 7;
    float acc = 0.f;
    for (int k = kh * 64; k < kh * 64 + 64; k++) {
        float hs = psum[0][k] + psum[1][k] + psum[2][k] + psum[3][k];
        acc = fmaf(hs, pw[k * 128 + e], acc);
    }
    ph[kh][e] = acc;
    __syncthreads();
    if (tid < 128) pooled[tid] = (ph[0][tid] + ph[1][tid]) * (1.f / 128.f) + pb[tid];
    __syncthreads();

    int t = tid & 63, kq = tid >> 6;
    float hacc = 0.f;
    for (int k = kq * 32; k < kq * 32 + 32; k++)
        hacc = fmaf(pooled[k], hw1[k * 64 + t], hacc);
    hq[kq][t] = hacc;
    __syncthreads();
    if (tid < 64) r1[tid] = fmaxf(hq[0][tid] + hq[1][tid] + hq[2][tid] + hq[3][tid] + hb1[tid], 0.f);
    __syncthreads();
    if (tid < OUTD) {
        float a = hb2[tid];
        #pragma unroll
        for (int k = 0; k < 64; k++) a = fmaf(r1[k], hw2[k * OUTD + tid], a);
        if (*flag) ((bf16*)outv)[b * OUTD + tid] = __float2bfloat16(a);
        else       ((float*)outv)[b * OUTD + tid] = a;
    }
}

extern "C" void kernel_launch(void* const* d_in, const int* in_sizes, int n_in,
                              void* d_out, int out_size, void* d_ws, size_t ws_size,
                              hipStream_t stream)
{
    float* ws = (float*)d_ws;
    float* pf = ws;                               // converted fp32 params [0..722432)
    const float* xf   = pf + 0;
    const float* cw   = pf + 294912;
    const float* cb   = pf + 296064;
    const float* bg   = pf + 296192;
    const float* bbt  = pf + 296320;
    const float* bm   = pf + 296448;
    const float* bv   = pf + 296576;
    const float* Wf   = pf + 296704;
    const float* asrcf= pf + 362240;
    const float* adstf= pf + 362752;
    const float* lng  = pf + 363264;
    const float* lnb  = pf + 363776;
    const float* fw1  = pf + 364288;
    const float* fb1  = pf + 495360;
    const float* fw2  = pf + 496384;
    const float* fb2  = pf + 627456;
    const float* ng   = pf + 627968;
    const float* nb   = pf + 628096;
    const float* pw   = pf + 628224;
    const float* pb   = pf + 644608;
    const float* hw1  = pf + 644736;
    const float* hb1  = pf + 652928;
    const float* hw2  = pf + 652992;
    const float* hb2  = pf + 656832;
    const float* sa   = pf + 656896;
    const float* wm   = pf + 673280;
    const float* wp   = pf + 689664;
    const float* ewa  = pf + 706048;

    int*   flag   = (int*)(ws + 722432);
    float* h      = ws + 722448;                  // 4,194,304 f32
    u16* h16    = (u16*)(h + 4194304);            // 4,194,304 u16
    u16* WT16   = h16 + 4194304;                  // 65,536
    u16* w1T16  = WT16 + 65536;                   // 131,072
    u16* w2T16  = w1T16 + 131072;                 // 131,072
    u16* Aw16   = w2T16 + 131072;                 // 16,384
    u16* ewam16 = Aw16 + 16384;                   // 16,384
    // total ~29 MB

    hipFuncSetAttribute((const void*)k_layer,
                        hipFuncAttributeMaxDynamicSharedMemorySize, LDS_BYTES);

    SrcPtrs S;
    for (int i = 0; i < 28; i++) S.p[i] = d_in[i];

    k_detect<<<1, 64, 0, stream>>>((const unsigned*)d_in[0], flag);
    k_convert<<<dim3(1152, 28), 256, 0, stream>>>(S, pf, flag);

    k_pack<<<1344, 256, 0, stream>>>(Wf, fw1, fw2, ewa, sa, WT16, w1T16, w2T16, ewam16);
    k_aw<<<NN, 128, 0, stream>>>(wp, wm, Aw16);
    k_embed<<<BB, 256, 0, stream>>>(xf, cw, cb, bg, bbt, bm, bv, h, h16);

    for (int i = 0; i < LLY; i++) {
        k_layer<<<BB, 512, LDS_BYTES, stream>>>(
            h, h16,
            WT16 + i * 16384, asrcf + i * 128, adstf + i * 128,
            Aw16, ewam16,
            lng + i * 128, lnb + i * 128,
            w1T16 + i * 32768, fb1 + i * 256,
            w2T16 + i * 32768, fb2 + i * 128);
    }

    k_final<<<BB, 256, 0, stream>>>(h, ng, nb, pw, pb, hw1, hb1, hw2, hb2, d_out, flag);
}

// Round 5
// 377.091 us; speedup vs baseline: 2.9919x; 1.1703x over previous
//
#include <hip/hip_runtime.h>
#include <hip/hip_bf16.h>

typedef __hip_bfloat16 bf16;
typedef unsigned short u16;
typedef __attribute__((ext_vector_type(8))) short bfrag;   // 8 bf16 = 4 VGPR
typedef __attribute__((ext_vector_type(4))) float cfrag;   // 4 f32 acc

union BF { bfrag v; u16 u[8]; unsigned w[4]; };
union CF { cfrag v; float f[4]; };

#define MFMA(a,b,c) __builtin_amdgcn_mfma_f32_16x16x32_bf16(a,b,c,0,0,0)

#define BB   256
#define NN   128
#define IND  9
#define HDD  128
#define NHH  8
#define LLY  4
#define OUTD 60
#define LOG2E 1.44269504f

__device__ __forceinline__ float b2f(bf16 v){ return __bfloat162float(v); }
__device__ __forceinline__ float u2f(u16 u){ return __uint_as_float(((unsigned)u) << 16); }
__device__ __forceinline__ u16 f2bf_bits(float f){
    unsigned u = __float_as_uint(f);
    return (u16)((u + 0x7FFFu + ((u >> 16) & 1u)) >> 16);   // RNE
}
__device__ __forceinline__ unsigned pk2(float a, float b){
    union { __hip_bfloat162 h; unsigned u; } c;
    c.h = __float22bfloat162_rn(make_float2(a, b));          // v_cvt_pk_bf16_f32
    return c.u;
}
__device__ __forceinline__ float wave_sum(float v){
    #pragma unroll
    for (int m = 32; m; m >>= 1) v += __shfl_xor(v, m, 64);
    return v;
}
__device__ __forceinline__ float ldin(const void* p, int i, bool isbf){
    return isbf ? b2f(((const bf16*)p)[i]) : ((const float*)p)[i];
}

struct SrcPtrs { const void* p[28]; };

__device__ const int CVT_SZ[28] = {
    294912,1152,128,128,128,128,128,65536,512,512,512,512,
    131072,1024,131072,512,128,128,16384,128,8192,64,3840,60,
    16384,16384,16384,16384};
__device__ const int CVT_OFF[28] = {
    0,294912,296064,296192,296320,296448,296576,296704,362240,362752,363264,363776,
    364288,495360,496384,627456,627968,628096,628224,644608,644736,652928,652992,656832,
    656896,673280,689664,706048};

// ====== fused prep: dtype-detect + convert + weight packs + ew2 + Aw ======
// block ranges: [0,2822) convert | [2822,3078) WT | [3078,3590) w1T
//               [3590,4102) w2T | [4102,4166) ew2 | [4166,4294) Aw rows
__global__ __launch_bounds__(256) void k_prep(
    SrcPtrs S, float* __restrict__ pf,
    u16* __restrict__ WT, u16* __restrict__ w1T, u16* __restrict__ w2T,
    u16* __restrict__ ew2, u16* __restrict__ Aw16, int* __restrict__ flagOut)
{
    // per-wave dtype detection: low halves of x words are sane bf16 iff input is bf16
    const unsigned* xw = (const unsigned*)S.p[0];
    int lane = threadIdx.x & 63;
    int cnt = 0;
    for (int i = lane; i < 512; i += 64) {
        float v = __uint_as_float((xw[i] & 0xFFFFu) << 16);
        if (!(fabsf(v) < 32.f)) cnt++;
    }
    bool isbf = wave_sum((float)cnt) < 16.f;
    if (blockIdx.x == 0 && threadIdx.x == 0) *flagOut = isbf ? 1 : 0;

    int blk = blockIdx.x, tid = threadIdx.x;
    if (blk < 2822) {                              // fp32 conversion of all inputs
        int idx = blk * 256 + tid;                 // < 722432 exactly
        int y = 27;
        for (int t = 1; t < 28; t++) if (idx < CVT_OFF[t]) { y = t - 1; break; }
        pf[idx] = ldin(S.p[y], idx - CVT_OFF[y], isbf);
    } else if (blk < 3078) {                       // WT[l][n128][k128] <- W[l][k][n]
        int j = (blk - 2822) * 256 + tid;
        int l = j >> 14, r = j & 16383, n = r >> 7, k = r & 127;
        WT[j] = f2bf_bits(ldin(S.p[7], (l << 14) + k * 128 + n, isbf));
    } else if (blk < 3590) {                       // w1T[l][n256][k128] <- fw1[l][k][n]
        int j = (blk - 3078) * 256 + tid;
        int l = j >> 15, r = j & 32767, n = r >> 7, k = r & 127;
        w1T[j] = f2bf_bits(ldin(S.p[12], (l << 15) + k * 256 + n, isbf));
    } else if (blk < 4102) {                       // w2T[l][n128][k256] <- fw2[l][k][n]
        int j = (blk - 3590) * 256 + tid;
        int l = j >> 15, r = j & 32767, n = r >> 8, k = r & 255;
        w2T[j] = f2bf_bits(ldin(S.p[14], (l << 15) + k * 128 + n, isbf));
    } else if (blk < 4166) {                       // ew2 = log2e * (mask ? ewa : -1e30)
        int j = (blk - 4102) * 256 + tid;
        float sav = ldin(S.p[24], j, isbf);
        float ewv = ldin(S.p[27], j, isbf);
        ew2[j] = f2bf_bits(sav > 0.f ? ewv * LOG2E : -1e30f);
    } else {                                       // Aw row-normalized, bf16
        __shared__ float red[2];
        int i = blk - 4166, j = tid & 127;
        float v = 0.f;
        if (tid < 128) {
            float wmv = ldin(S.p[25], i * 128 + j, isbf);
            float wpv = ldin(S.p[26], i * 128 + j, isbf);
            v = wmv / (1.f + __expf(-wpv));
            float sm = wave_sum(v);
            if ((tid & 63) == 0) red[tid >> 6] = sm;
        }
        __syncthreads();
        if (tid < 128) {
            float tot = red[0] + red[1];
            Aw16[i * 128 + j] = f2bf_bits(v / (tot + 1e-5f));
        }
    }
}

// ====== embedding: conv1d(k=1) + eval BN + relu ======
__global__ __launch_bounds__(256) void k_embed(
    const float* __restrict__ xf, const float* __restrict__ cw, const float* __restrict__ cb,
    const float* __restrict__ bg, const float* __restrict__ bbt,
    const float* __restrict__ bm, const float* __restrict__ bv,
    float* __restrict__ h, u16* __restrict__ h16)
{
    int b = blockIdx.x, tid = threadIdx.x;
    int d = tid & 127, nh = tid >> 7;
    float wreg[IND];
    #pragma unroll
    for (int k = 0; k < IND; k++) wreg[k] = cw[d * IND + k];
    float scale = rsqrtf(bv[d] + 1e-5f) * bg[d];
    float bias  = bbt[d] - bm[d] * scale;
    float cbd   = cb[d];
    for (int it = 0; it < 64; it++) {
        int bn = b * NN + it * 2 + nh;             // wave-uniform
        float acc = cbd;
        #pragma unroll
        for (int k = 0; k < IND; k++) acc = fmaf(xf[bn * IND + k], wreg[k], acc);
        acc = fmaxf(fmaf(acc, scale, bias), 0.f);
        h[bn * HDD + d] = acc;
        h16[bn * HDD + d] = f2bf_bits(acc);
    }
}

// ====== per-layer megakernel: grid (256 graphs x 2 halves), 256 thr = 4 waves ======
// Each block: full hp GEMM + s/t (duplicated, cheap), then 64 output rows.
__global__ __launch_bounds__(256, 2) void k_layer(
    float* __restrict__ hg, u16* __restrict__ h16g,
    const u16* __restrict__ WT,
    const float* __restrict__ asrc, const float* __restrict__ adst,
    const u16* __restrict__ Aw16, const u16* __restrict__ ew2g,
    const float* __restrict__ lng, const float* __restrict__ lnb,
    const u16* __restrict__ w1T, const float* __restrict__ b1,
    const u16* __restrict__ w2T, const float* __restrict__ b2,
    const float* __restrict__ ng, const float* __restrict__ nb,
    float* __restrict__ pooled, int last)
{
    __shared__ __align__(16) u16 hpT[128 * 136];   // hp^T [dim][node] 34,816 B
    __shared__ __align__(16) u16 gbuf[64 * 136];   // g (local rows)   17,408 B
    __shared__ float st2[2048];                    // s2|t2 (scaled by log2e); psum alias
    __shared__ float lng_s[128], lnb_s[128], b2_s[128], ng_s[128], nb_s[128];
    __shared__ float b1_s[256];
    u16* hidb = hpT;                               // alias: hpT dead after phase 4
    float* s2 = st2;
    float* t2 = st2 + 1024;

    const int b = blockIdx.x, half = blockIdx.y;
    const int tid = threadIdx.x, lane = tid & 63, wv = tid >> 6;
    const int l15 = lane & 15, kg = lane >> 4;
    const int wrow = wv * 16;                      // local row-tile base (phases 3-6)
    const int base = b * NN;

    if (tid < 128) {
        lng_s[tid] = lng[tid]; lnb_s[tid] = lnb[tid]; b2_s[tid] = b2[tid];
        if (last) { ng_s[tid] = ng[tid]; nb_s[tid] = nb[tid]; }
    }
    b1_s[tid] = b1[tid];

    // ---------- Phase 1: full hp = h @ W (M=128), 32 rows/wave ----------
    {
        CF acc[2][8];
        #pragma unroll
        for (int mt = 0; mt < 2; mt++)
            #pragma unroll
            for (int nt = 0; nt < 8; nt++)
                #pragma unroll
                for (int r = 0; r < 4; r++) acc[mt][nt].f[r] = 0.f;
        #pragma unroll
        for (int kk = 0; kk < 4; kk++) {
            bfrag af[2];
            #pragma unroll
            for (int mt = 0; mt < 2; mt++)
                af[mt] = *(const bfrag*)&h16g[(base + wv*32 + mt*16 + l15) * 128 + kk*32 + kg*8];
            #pragma unroll
            for (int nt = 0; nt < 8; nt++) {
                bfrag bw = *(const bfrag*)&WT[(nt*16 + l15) * 128 + kk*32 + kg*8];
                #pragma unroll
                for (int mt = 0; mt < 2; mt++)
                    acc[mt][nt].v = MFMA(af[mt], bw, acc[mt][nt].v);
            }
        }
        #pragma unroll
        for (int mt = 0; mt < 2; mt++)
            #pragma unroll
            for (int nt = 0; nt < 8; nt++) {
                int col = nt*16 + l15;
                #pragma unroll
                for (int rp = 0; rp < 2; rp++) {
                    int row = wv*32 + mt*16 + kg*4 + rp*2;
                    *(unsigned*)&hpT[col * 136 + row] =
                        pk2(acc[mt][nt].f[rp*2], acc[mt][nt].f[rp*2+1]);
                }
            }
    }
    __syncthreads();

    // ---------- Phase 2: s,t head scores for ALL nodes, pre-scaled by log2e ----------
    {
        int node = tid & 127, which = tid >> 7;
        const float* av = which ? adst : asrc;
        float* dst = which ? t2 : s2;
        #pragma unroll
        for (int h = 0; h < 8; h++) {
            float a = 0.f;
            #pragma unroll
            for (int d = 0; d < 16; d++)
                a = fmaf(u2f(hpT[(h*16 + d) * 136 + node]), av[h*16 + d], a);
            dst[h * 128 + node] = a * LOG2E;
        }
    }
    __syncthreads();

    // ---------- Phase 3: softmax (exp2 form, no max-sub) + strong MFMA ----------
    CF accS[8];
    #pragma unroll
    for (int nt = 0; nt < 8; nt++)
        #pragma unroll
        for (int r = 0; r < 4; r++) accS[nt].f[r] = 0.f;

    const int grow = half*64 + wrow + l15;         // A-frag row: global node i
    float ew2f[4][8];
    #pragma unroll
    for (int kk = 0; kk < 4; kk++) {
        BF e2; e2.v = *(const bfrag*)&ew2g[grow * 128 + kk*32 + kg*8];
        #pragma unroll
        for (int j = 0; j < 8; j++) ew2f[kk][j] = u2f(e2.u[j]);
    }
    #pragma unroll 1
    for (int h = 0; h < 8; h++) {
        bfrag hb[4];
        #pragma unroll
        for (int kk = 0; kk < 4; kk++)
            hb[kk] = *(const bfrag*)&hpT[(h*16 + l15) * 136 + kk*32 + kg*8];
        float sA = s2[h * 128 + grow];
        float pv[4][8];
        float sm = 0.f;
        #pragma unroll
        for (int kk = 0; kk < 4; kk++) {
            const float* tp = &t2[h * 128 + kk*32 + kg*8];
            #pragma unroll
            for (int j = 0; j < 8; j++) {
                float x2 = sA + tp[j];
                float lk = fmaxf(x2, 0.2f * x2);               // log2e*leaky(s+t)
                float p = __builtin_amdgcn_exp2f(lk + ew2f[kk][j]);  // masked -> 0
                pv[kk][j] = p; sm += p;
            }
        }
        sm += __shfl_xor(sm, 16, 64);
        sm += __shfl_xor(sm, 32, 64);
        float inv = __builtin_amdgcn_rcpf(sm);
        #pragma unroll
        for (int kk = 0; kk < 4; kk++) {
            BF pb;
            #pragma unroll
            for (int q = 0; q < 4; q++)
                pb.w[q] = pk2(pv[kk][2*q] * inv, pv[kk][2*q+1] * inv);
            accS[h].v = MFMA(pb.v, hb[kk], accS[h].v);
        }
    }

    // ---------- Phase 4: weak = Aw @ hp ----------
    CF accW[8];
    #pragma unroll
    for (int nt = 0; nt < 8; nt++)
        #pragma unroll
        for (int r = 0; r < 4; r++) accW[nt].f[r] = 0.f;
    #pragma unroll
    for (int kk = 0; kk < 4; kk++) {
        bfrag awf = *(const bfrag*)&Aw16[grow * 128 + kk*32 + kg*8];
        #pragma unroll
        for (int nt = 0; nt < 8; nt++) {
            bfrag hb2 = *(const bfrag*)&hpT[(nt*16 + l15) * 136 + kk*32 + kg*8];
            accW[nt].v = MFMA(awf, hb2, accW[nt].v);
        }
    }

    // ---------- Phase 5: g = relu(0.6 s + 0.4 w), LN, write gbuf (local rows) ----------
    {
        float gv[8][4];
        #pragma unroll
        for (int nt = 0; nt < 8; nt++)
            #pragma unroll
            for (int r = 0; r < 4; r++)
                gv[nt][r] = fmaxf(0.6f * accS[nt].f[r] + 0.4f * accW[nt].f[r], 0.f);
        #pragma unroll
        for (int r = 0; r < 4; r++) {
            float s1 = 0.f, sq = 0.f;
            #pragma unroll
            for (int nt = 0; nt < 8; nt++) { float x = gv[nt][r]; s1 += x; sq = fmaf(x, x, sq); }
            #pragma unroll
            for (int m = 1; m <= 8; m <<= 1) { s1 += __shfl_xor(s1, m, 64); sq += __shfl_xor(sq, m, 64); }
            float mu = s1 * (1.f / 128.f);
            float var = sq * (1.f / 128.f) - mu * mu;
            float rs = rsqrtf(fmaxf(var, 0.f) + 1e-5f);
            int lrow = wrow + kg*4 + r;
            #pragma unroll
            for (int nt = 0; nt < 8; nt++) {
                int col = nt*16 + l15;
                gbuf[lrow * 136 + col] = f2bf_bits(fmaf((gv[nt][r] - mu) * rs, lng_s[col], lnb_s[col]));
            }
        }
    }
    __syncthreads();

    // ---------- Phase 6: FFN (M=64), two N-halves through LDS ----------
    CF acc2[8];
    #pragma unroll
    for (int nt = 0; nt < 8; nt++)
        #pragma unroll
        for (int r = 0; r < 4; r++) acc2[nt].f[r] = 0.f;

    #pragma unroll 1
    for (int nh = 0; nh < 2; nh++) {
        CF a1[8];
        #pragma unroll
        for (int nt = 0; nt < 8; nt++)
            #pragma unroll
            for (int r = 0; r < 4; r++) a1[nt].f[r] = 0.f;
        #pragma unroll
        for (int kk = 0; kk < 4; kk++) {
            bfrag gf = *(const bfrag*)&gbuf[(wrow + l15) * 136 + kk*32 + kg*8];
            #pragma unroll
            for (int nt = 0; nt < 8; nt++) {
                bfrag wf = *(const bfrag*)&w1T[(nh*128 + nt*16 + l15) * 128 + kk*32 + kg*8];
                a1[nt].v = MFMA(gf, wf, a1[nt].v);
            }
        }
        __syncthreads();                           // hidb region free (hpT readers done)
        #pragma unroll
        for (int nt = 0; nt < 8; nt++) {
            int col = nt*16 + l15;
            #pragma unroll
            for (int r = 0; r < 4; r++) {
                int lrow = wrow + kg*4 + r;
                hidb[lrow * 136 + col] = f2bf_bits(fmaxf(a1[nt].f[r] + b1_s[nh*128 + col], 0.f));
            }
        }
        __syncthreads();
        #pragma unroll
        for (int kk = 0; kk < 4; kk++) {
            bfrag hf = *(const bfrag*)&hidb[(wrow + l15) * 136 + kk*32 + kg*8];
            #pragma unroll
            for (int nt = 0; nt < 8; nt++) {
                bfrag wf = *(const bfrag*)&w2T[(nt*16 + l15) * 256 + nh*128 + kk*32 + kg*8];
                acc2[nt].v = MFMA(hf, wf, acc2[nt].v);
            }
        }
    }

    // ---------- Epilogue ----------
    float hv[8][4];
    #pragma unroll
    for (int nt = 0; nt < 8; nt++) {
        int col = nt*16 + l15;
        #pragma unroll
        for (int r = 0; r < 4; r++) {
            int gi = (base + half*64 + wrow + kg*4 + r) * HDD + col;
            hv[nt][r] = acc2[nt].f[r] + b2_s[col] + hg[gi];
        }
    }
    if (!last) {
        #pragma unroll
        for (int nt = 0; nt < 8; nt++) {
            int col = nt*16 + l15;
            #pragma unroll
            for (int r = 0; r < 4; r++) {
                int gi = (base + half*64 + wrow + kg*4 + r) * HDD + col;
                hg[gi] = hv[nt][r];
                h16g[gi] = f2bf_bits(hv[nt][r]);
            }
        }
    } else {
        // final LN per row + node-sum (pre-proj; proj commutes with mean) -> pooled
        float pacc[8];
        #pragma unroll
        for (int nt = 0; nt < 8; nt++) pacc[nt] = 0.f;
        #pragma unroll
        for (int r = 0; r < 4; r++) {
            float s1 = 0.f, sq = 0.f;
            #pragma unroll
            for (int nt = 0; nt < 8; nt++) { float x = hv[nt][r]; s1 += x; sq = fmaf(x, x, sq); }
            #pragma unroll
            for (int m = 1; m <= 8; m <<= 1) { s1 += __shfl_xor(s1, m, 64); sq += __shfl_xor(sq, m, 64); }
            float mu = s1 * (1.f / 128.f);
            float var = sq * (1.f / 128.f) - mu * mu;
            float rs = rsqrtf(fmaxf(var, 0.f) + 1e-5f);
            #pragma unroll
            for (int nt = 0; nt < 8; nt++) {
                int col = nt*16 + l15;
                pacc[nt] += fmaf((hv[nt][r] - mu) * rs, ng_s[col], nb_s[col]);
            }
        }
        __syncthreads();                           // st2 safe to reuse as psum
        float* psum = st2;                         // [16][128]
        #pragma unroll
        for (int nt = 0; nt < 8; nt++)
            psum[(wv*4 + kg) * 128 + nt*16 + l15] = pacc[nt];
        __syncthreads();
        if (tid < 128) {
            float tot = 0.f;
            #pragma unroll
            for (int i = 0; i < 16; i++) tot += psum[i * 128 + tid];
            atomicAdd(&pooled[b * HDD + tid], tot);
        }
    }
}

// ====== head: proj(mean) + MLP ======
__global__ __launch_bounds__(128) void k_head(
    const float* __restrict__ pooled, const float* __restrict__ pw, const float* __restrict__ pb,
    const float* __restrict__ hw1, const float* __restrict__ hb1,
    const float* __restrict__ hw2, const float* __restrict__ hb2,
    void* __restrict__ outv, const int* __restrict__ flag)
{
    int b = blockIdx.x, t = threadIdx.x;
    __shared__ float pm[128], pr[128], r1[64];
    pm[t] = pooled[b * HDD + t] * (1.f / 128.f);
    __syncthreads();
    float a = pb[t];
    for (int k = 0; k < 128; k++) a = fmaf(pm[k], pw[k * 128 + t], a);
    pr[t] = a;
    __syncthreads();
    if (t < 64) {
        float a1 = hb1[t];
        for (int k = 0; k < 128; k++) a1 = fmaf(pr[k], hw1[k * 64 + t], a1);
        r1[t] = fmaxf(a1, 0.f);
    }
    __syncthreads();
    if (t < OUTD) {
        float a2 = hb2[t];
        #pragma unroll
        for (int k = 0; k < 64; k++) a2 = fmaf(r1[k], hw2[k * OUTD + t], a2);
        if (*flag) ((bf16*)outv)[b * OUTD + t] = __float2bfloat16(a2);
        else       ((float*)outv)[b * OUTD + t] = a2;
    }
}

extern "C" void kernel_launch(void* const* d_in, const int* in_sizes, int n_in,
                              void* d_out, int out_size, void* d_ws, size_t ws_size,
                              hipStream_t stream)
{
    float* ws = (float*)d_ws;
    float* pf = ws;                                // converted fp32 params [0..722432)
    const float* xf   = pf + 0;
    const float* cw   = pf + 294912;
    const float* cb   = pf + 296064;
    const float* bg   = pf + 296192;
    const float* bbt  = pf + 296320;
    const float* bm   = pf + 296448;
    const float* bv   = pf + 296576;
    const float* asrcf= pf + 362240;
    const float* adstf= pf + 362752;
    const float* lng  = pf + 363264;
    const float* lnb  = pf + 363776;
    const float* fb1  = pf + 495360;
    const float* fb2  = pf + 627456;
    const float* ng   = pf + 627968;
    const float* nb   = pf + 628096;
    const float* pw   = pf + 628224;
    const float* pb   = pf + 644608;
    const float* hw1  = pf + 644736;
    const float* hb1  = pf + 652928;
    const float* hw2  = pf + 652992;
    const float* hb2  = pf + 656832;

    int*   flag   = (int*)(ws + 722432);
    float* h      = ws + 722448;                   // 4,194,304 f32
    float* pooled = h + 4194304;                   // 32,768 f32
    u16* h16    = (u16*)(pooled + 32768);          // 4,194,304 u16
    u16* WT16   = h16 + 4194304;                   // 65,536
    u16* w1T16  = WT16 + 65536;                    // 131,072
    u16* w2T16  = w1T16 + 131072;                  // 131,072
    u16* Aw16   = w2T16 + 131072;                  // 16,384
    u16* ew2p   = Aw16 + 16384;                    // 16,384
    // total ~28 MB

    SrcPtrs S;
    for (int i = 0; i < 28; i++) S.p[i] = d_in[i];

    k_prep<<<4294, 256, 0, stream>>>(S, pf, WT16, w1T16, w2T16, ew2p, Aw16, flag);
    hipMemsetAsync(pooled, 0, BB * HDD * sizeof(float), stream);
    k_embed<<<BB, 256, 0, stream>>>(xf, cw, cb, bg, bbt, bm, bv, h, h16);

    for (int i = 0; i < LLY; i++) {
        k_layer<<<dim3(BB, 2), 256, 0, stream>>>(
            h, h16,
            WT16 + i * 16384, asrcf + i * 128, adstf + i * 128,
            Aw16, ew2p,
            lng + i * 128, lnb + i * 128,
            w1T16 + i * 32768, fb1 + i * 256,
            w2T16 + i * 32768, fb2 + i * 128,
            ng, nb, pooled, (i == LLY - 1) ? 1 : 0);
    }

    k_head<<<BB, 128, 0, stream>>>(pooled, pw, pb, hw1, hb1, hw2, hb2, d_out, flag);
}